// Round 4
// baseline (428.702 us; speedup 1.0000x reference)
//
#include <hip/hip_runtime.h>
#include <hip/hip_bf16.h>

typedef __attribute__((ext_vector_type(8))) short bf16x8;
typedef __attribute__((ext_vector_type(4))) float f32x4;
typedef __attribute__((ext_vector_type(8))) unsigned short u16x8;

#define LDS_AS3(p) ((__attribute__((address_space(3))) void*)(p))
#define GLB_AS1(p) ((const __attribute__((address_space(1))) void*)(p))

__device__ inline unsigned short f2bf(float f) {
    unsigned int x = __float_as_uint(f);
    unsigned int r = (x + 0x7fffu + ((x >> 16) & 1u)) >> 16;  // RNE, no NaN in data
    return (unsigned short)r;
}
__device__ inline float bf2f(unsigned short b) {
    return __uint_as_float(((unsigned int)b) << 16);
}

// ---------------- fp32 -> bf16 for Q and K (grid.y selects input) ----------------
__global__ __launch_bounds__(256) void conv_qk(const float4* __restrict__ q,
                                               const float4* __restrict__ k,
                                               ushort4* __restrict__ Q16,
                                               ushort4* __restrict__ K16, int n4) {
    const float4* in = blockIdx.y ? k : q;
    ushort4* out = blockIdx.y ? K16 : Q16;
    int i = blockIdx.x * 256 + threadIdx.x;
    if (i < n4) {
        float4 f = in[i];
        ushort4 o;
        o.x = f2bf(f.x); o.y = f2bf(f.y); o.z = f2bf(f.z); o.w = f2bf(f.w);
        out[i] = o;
    }
}

// ---------------- V [S,D] fp32 -> VT [D,S] bf16 (per batch) ----------------
__global__ __launch_bounds__(256) void transpose_conv(const float* __restrict__ V,
                                                      unsigned short* __restrict__ VT,
                                                      int rows, int cols) {
    __shared__ unsigned short tile[32][33];
    long b = blockIdx.z;
    V  += b * (long)rows * cols;
    VT += b * (long)rows * cols;
    int n0 = blockIdx.x * 32, k0 = blockIdx.y * 32;
    int tx = threadIdx.x, ty = threadIdx.y;
#pragma unroll
    for (int j = 0; j < 4; ++j)
        tile[ty + j * 8][tx] = f2bf(V[(long)(k0 + ty + j * 8) * cols + n0 + tx]);
    __syncthreads();
#pragma unroll
    for (int j = 0; j < 4; ++j)
        VT[(long)(n0 + ty + j * 8) * rows + k0 + tx] = tile[tx][ty + j * 8];
}

// ---------------- GEMM1: E = exp2(c * Q K^T) bf16 + row-sum partials ----------------
// 128x128 tile, 4 waves, BK=64, 2-phase dbuf pipeline (stage t+1 before compute t,
// one barrier per K-step), XCD-aware bijective swizzle (batch-major per XCD).
__global__ __launch_bounds__(256) void gemm_qk_exp(
    const unsigned short* __restrict__ Qg,  // [B,S,D] bf16
    const unsigned short* __restrict__ Kg,  // [B,S,D] bf16
    unsigned short* __restrict__ E,         // [B,S,S] bf16
    float* __restrict__ psum)               // [B*S][32]
{
    __shared__ __attribute__((aligned(16))) unsigned short As[2][128][64];
    __shared__ __attribute__((aligned(16))) unsigned short Bs[2][128][64];
    const int S = 2048, D = 512;

    // nwg = 2048; chunked XCD swizzle: tile = (wg%8)*256 + wg/8
    int wg = blockIdx.x;
    int tile = (wg & 7) * 256 + (wg >> 3);
    int b = tile >> 8;  // 256 tiles (16x16) per batch
    int rem = tile & 255;
    int by = rem >> 4, bx = rem & 15;

    const unsigned short* Ab = Qg + ((long)b * S + by * 128) * D;
    const unsigned short* Bb = Kg + ((long)b * S + bx * 128) * D;
    unsigned short* Eb = E + (long)b * S * S;

    const int tid = threadIdx.x;
    const int lane = tid & 63, w = tid >> 6;
    const int wr = (w >> 1) * 64, wc = (w & 1) * 64;
    const int fr = lane & 15, fq = lane >> 4;

    f32x4 acc[4][4] = {};

    // NOTE: kk evaluated ONCE at entry; inner loop var is ti (round-3 bug: the
    // inner loop shadowed the caller's `t` inside the k0 expression).
#define STAGE1(buf, k0expr)                                                        \
    {                                                                              \
        const int kk = (k0expr);                                                   \
        char* Ad = (char*)&As[buf][0][0];                                          \
        char* Bd = (char*)&Bs[buf][0][0];                                          \
        _Pragma("unroll") for (int ti = 0; ti < 4; ++ti) {                         \
            int c = tid + 256 * ti;                                                \
            int r = c >> 3, col = (c & 7) << 3;                                    \
            int off = (w * 64 + 256 * ti) * 16;                                    \
            __builtin_amdgcn_global_load_lds(GLB_AS1(Ab + (long)r * D + kk + col), \
                                             LDS_AS3(Ad + off), 16, 0, 0);         \
            __builtin_amdgcn_global_load_lds(GLB_AS1(Bb + (long)r * D + kk + col), \
                                             LDS_AS3(Bd + off), 16, 0, 0);         \
        }                                                                          \
    }

    STAGE1(0, 0);
    __syncthreads();

    for (int t = 0; t < 8; ++t) {  // K = 512 = 8 * 64
        int cur = t & 1;
        if (t < 7) STAGE1(cur ^ 1, (t + 1) * 64);
#pragma unroll
        for (int ks = 0; ks < 2; ++ks) {
            bf16x8 af[4], bv[4];
#pragma unroll
            for (int i = 0; i < 4; ++i)
                af[i] = *(const bf16x8*)&As[cur][wr + i * 16 + fr][ks * 32 + fq * 8];
#pragma unroll
            for (int j = 0; j < 4; ++j)
                bv[j] = *(const bf16x8*)&Bs[cur][wc + j * 16 + fr][ks * 32 + fq * 8];
#pragma unroll
            for (int i = 0; i < 4; ++i)
#pragma unroll
                for (int j = 0; j < 4; ++j)
                    acc[i][j] = __builtin_amdgcn_mfma_f32_16x16x32_bf16(
                        af[i], bv[j], acc[i][j], 0, 0, 0);
        }
        __syncthreads();
    }
#undef STAGE1

    // ---- epilogue: exp2, bf16 store, row partial sums ----
    const float cexp = (float)(1.4426950408889634 / 45.254833995939045);  // log2e/sqrt(2048)
    float ps[4][4];
#pragma unroll
    for (int i = 0; i < 4; ++i)
#pragma unroll
        for (int r = 0; r < 4; ++r) ps[i][r] = 0.f;

#pragma unroll
    for (int i = 0; i < 4; ++i) {
        int row0 = by * 128 + wr + i * 16 + fq * 4;
#pragma unroll
        for (int j = 0; j < 4; ++j) {
            int colc = bx * 128 + wc + j * 16 + fr;
#pragma unroll
            for (int r = 0; r < 4; ++r) {
                float e = exp2f(acc[i][j][r] * cexp);
                unsigned short eb = f2bf(e);
                Eb[(long)(row0 + r) * S + colc] = eb;
                ps[i][r] += bf2f(eb);
            }
        }
    }
#pragma unroll
    for (int i = 0; i < 4; ++i)
#pragma unroll
        for (int r = 0; r < 4; ++r) {
            float v = ps[i][r];
#pragma unroll
            for (int off = 1; off < 16; off <<= 1) v += __shfl_xor(v, off);
            ps[i][r] = v;
        }
    if (fr == 0) {
        int slot = bx * 2 + (w & 1);
#pragma unroll
        for (int i = 0; i < 4; ++i) {
            int row0 = by * 128 + wr + i * 16 + fq * 4;
#pragma unroll
            for (int r = 0; r < 4; ++r)
                psum[((long)b * S + row0 + r) * 32 + slot] = ps[i][r];
        }
    }
}

// ---------------- GEMM2: O = (E VT^T) * inv ; bx==0 blocks also emit Pout = E*inv ----
__global__ __launch_bounds__(256) void gemm_pv_norm(
    const unsigned short* __restrict__ Eg,   // [B,S,S] bf16
    const unsigned short* __restrict__ VTg,  // [B,D,S] bf16
    const float* __restrict__ psum,          // [B*S][32]
    float* __restrict__ Pout,                // [B,S,S] fp32
    float* __restrict__ O)                   // [B,S,D] fp32
{
    __shared__ __attribute__((aligned(16))) unsigned short As[2][128][64];
    __shared__ __attribute__((aligned(16))) unsigned short Bs[2][128][64];
    __shared__ float invRow[128];
    const int S = 2048, D = 512;

    // nwg = 512; chunked XCD swizzle: tile = (wg%8)*64 + wg/8
    int wg = blockIdx.x;
    int tile = (wg & 7) * 64 + (wg >> 3);
    int b = tile >> 6;  // 64 tiles (16 by x 4 bx) per batch
    int rem = tile & 63;
    int by = rem >> 2, bx = rem & 3;

    const unsigned short* Ab = Eg + ((long)b * S + by * 128) * S;
    const unsigned short* Bb = VTg + ((long)b * D + bx * 128) * S;

    const int tid = threadIdx.x;
    const int lane = tid & 63, w = tid >> 6;
    const int wr = (w >> 1) * 64, wc = (w & 1) * 64;
    const int fr = lane & 15, fq = lane >> 4;

#define STAGE2(buf, k0expr)                                                        \
    {                                                                              \
        const int kk = (k0expr);                                                   \
        char* Ad = (char*)&As[buf][0][0];                                          \
        char* Bd = (char*)&Bs[buf][0][0];                                          \
        _Pragma("unroll") for (int ti = 0; ti < 4; ++ti) {                         \
            int c = tid + 256 * ti;                                                \
            int r = c >> 3, col = (c & 7) << 3;                                    \
            int off = (w * 64 + 256 * ti) * 16;                                    \
            __builtin_amdgcn_global_load_lds(GLB_AS1(Ab + (long)r * S + kk + col), \
                                             LDS_AS3(Ad + off), 16, 0, 0);         \
            __builtin_amdgcn_global_load_lds(GLB_AS1(Bb + (long)r * S + kk + col), \
                                             LDS_AS3(Bd + off), 16, 0, 0);         \
        }                                                                          \
    }

    STAGE2(0, 0);

    // row-sum reduction -> 1/sum for this block's 128 rows (overlaps stage 0)
    if (tid < 128) {
        const float4* p4 = (const float4*)(psum + ((long)b * S + by * 128 + tid) * 32);
        float s = 0.f;
#pragma unroll
        for (int i = 0; i < 8; ++i) {
            float4 v = p4[i];
            s += v.x + v.y + v.z + v.w;
        }
        invRow[tid] = 1.0f / s;
    }

    f32x4 acc[4][4] = {};
    __syncthreads();

    // Pout-writer role (bx==0 blocks): thread -> (row, 32-col half)
    const int prRow = tid >> 1, prC0 = (tid & 1) * 32;
    const float ivP = invRow[prRow];
    float* prow = Pout + ((long)b * S + by * 128 + prRow) * S + prC0;

    for (int t = 0; t < 32; ++t) {  // K = 2048 = 32 * 64
        int cur = t & 1;
        if (t < 31) STAGE2(cur ^ 1, (t + 1) * 64);
#pragma unroll
        for (int ks = 0; ks < 2; ++ks) {
            bf16x8 af[4], bv[4];
#pragma unroll
            for (int i = 0; i < 4; ++i)
                af[i] = *(const bf16x8*)&As[cur][wr + i * 16 + fr][ks * 32 + fq * 8];
#pragma unroll
            for (int j = 0; j < 4; ++j)
                bv[j] = *(const bf16x8*)&Bs[cur][wc + j * 16 + fr][ks * 32 + fq * 8];
#pragma unroll
            for (int i = 0; i < 4; ++i)
#pragma unroll
                for (int j = 0; j < 4; ++j)
                    acc[i][j] = __builtin_amdgcn_mfma_f32_16x16x32_bf16(
                        af[i], bv[j], acc[i][j], 0, 0, 0);
        }
        if (bx == 0) {
            // normalize this A-tile from LDS -> fp32 attention-weights output
#pragma unroll
            for (int u = 0; u < 4; ++u) {
                u16x8 ev = *(const u16x8*)&As[cur][prRow][prC0 + u * 8];
                float4 o0 = {bf2f(ev[0]) * ivP, bf2f(ev[1]) * ivP,
                             bf2f(ev[2]) * ivP, bf2f(ev[3]) * ivP};
                float4 o1 = {bf2f(ev[4]) * ivP, bf2f(ev[5]) * ivP,
                             bf2f(ev[6]) * ivP, bf2f(ev[7]) * ivP};
                *(float4*)(prow + t * 64 + u * 8) = o0;
                *(float4*)(prow + t * 64 + u * 8 + 4) = o1;
            }
        }
        __syncthreads();
    }
#undef STAGE2

    // ---- epilogue: O = acc * inv[row] ----
#pragma unroll
    for (int i = 0; i < 4; ++i) {
        int lr0 = wr + i * 16 + fq * 4;
        float iv[4];
#pragma unroll
        for (int r = 0; r < 4; ++r) iv[r] = invRow[lr0 + r];
        int row0 = by * 128 + lr0;
#pragma unroll
        for (int j = 0; j < 4; ++j) {
            int colc = bx * 128 + wc + j * 16 + fr;
#pragma unroll
            for (int r = 0; r < 4; ++r)
                O[((long)b * S + row0 + r) * D + colc] = acc[i][j][r] * iv[r];
        }
    }
}

extern "C" void kernel_launch(void* const* d_in, const int* in_sizes, int n_in,
                              void* d_out, int out_size, void* d_ws, size_t ws_size,
                              hipStream_t stream) {
    const int B = 8, S = 2048, D = 512;
    const float* q = (const float*)d_in[0];
    const float* k = (const float*)d_in[1];
    const float* v = (const float*)d_in[2];

    float* Oout = (float*)d_out;             // [B,S,D]
    float* Pout = Oout + (size_t)B * S * D;  // [B,S,S]

    unsigned short* Q16 = (unsigned short*)d_ws;      // B*S*D bf16
    unsigned short* K16 = Q16 + (size_t)B * S * D;    // B*S*D bf16
    unsigned short* VT16 = K16 + (size_t)B * S * D;   // B*D*S bf16
    unsigned short* E16 = VT16 + (size_t)B * S * D;   // B*S*S bf16
    float* psum = (float*)(E16 + (size_t)B * S * S);  // B*S*32 fp32

    int n4 = B * S * D / 4;
    conv_qk<<<dim3(n4 / 256, 2), 256, 0, stream>>>((const float4*)q, (const float4*)k,
                                                   (ushort4*)Q16, (ushort4*)K16, n4);
    transpose_conv<<<dim3(D / 32, S / 32, B), dim3(32, 8), 0, stream>>>(v, VT16, S, D);

    gemm_qk_exp<<<2048, 256, 0, stream>>>(Q16, K16, E16, psum);

    gemm_pv_norm<<<512, 256, 0, stream>>>(E16, VT16, psum, Pout, Oout);
}

// Round 5
// 377.623 us; speedup vs baseline: 1.1353x; 1.1353x over previous
//
#include <hip/hip_runtime.h>
#include <hip/hip_bf16.h>

typedef __attribute__((ext_vector_type(8))) short bf16x8;
typedef __attribute__((ext_vector_type(4))) float f32x4;
typedef __attribute__((ext_vector_type(8))) unsigned short u16x8;

#define LDS_AS3(p) ((__attribute__((address_space(3))) void*)(p))
#define GLB_AS1(p) ((const __attribute__((address_space(1))) void*)(p))

__device__ inline unsigned short f2bf(float f) {
    unsigned int x = __float_as_uint(f);
    unsigned int r = (x + 0x7fffu + ((x >> 16) & 1u)) >> 16;  // RNE, no NaN in data
    return (unsigned short)r;
}
__device__ inline float bf2f(unsigned short b) {
    return __uint_as_float(((unsigned int)b) << 16);
}

// ---------------- fp32 -> bf16 for Q and K (grid.y selects input) ----------------
__global__ __launch_bounds__(256) void conv_qk(const float4* __restrict__ q,
                                               const float4* __restrict__ k,
                                               ushort4* __restrict__ Q16,
                                               ushort4* __restrict__ K16, int n4) {
    const float4* in = blockIdx.y ? k : q;
    ushort4* out = blockIdx.y ? K16 : Q16;
    int i = blockIdx.x * 256 + threadIdx.x;
    if (i < n4) {
        float4 f = in[i];
        ushort4 o;
        o.x = f2bf(f.x); o.y = f2bf(f.y); o.z = f2bf(f.z); o.w = f2bf(f.w);
        out[i] = o;
    }
}

// ---------------- V [S,D] fp32 -> VT [D,S] bf16 (per batch) ----------------
__global__ __launch_bounds__(256) void transpose_conv(const float* __restrict__ V,
                                                      unsigned short* __restrict__ VT,
                                                      int rows, int cols) {
    __shared__ unsigned short tile[32][33];
    long b = blockIdx.z;
    V  += b * (long)rows * cols;
    VT += b * (long)rows * cols;
    int n0 = blockIdx.x * 32, k0 = blockIdx.y * 32;
    int tx = threadIdx.x, ty = threadIdx.y;
#pragma unroll
    for (int j = 0; j < 4; ++j)
        tile[ty + j * 8][tx] = f2bf(V[(long)(k0 + ty + j * 8) * cols + n0 + tx]);
    __syncthreads();
#pragma unroll
    for (int j = 0; j < 4; ++j)
        VT[(long)(n0 + ty + j * 8) * rows + k0 + tx] = tile[tx][ty + j * 8];
}

// ---------------- GEMM1: E = exp2(c * Q K^T) bf16 + row-sum partials ----------------
// 128x128 tile, 4 waves, BK=64, SINGLE-buffer LDS (32KB -> 5 blocks/CU),
// XCD-aware batch-major swizzle (Q_b,K_b 2MB+2MB fit one XCD's 4MB L2).
__global__ __launch_bounds__(256) void gemm_qk_exp(
    const unsigned short* __restrict__ Qg,  // [B,S,D] bf16
    const unsigned short* __restrict__ Kg,  // [B,S,D] bf16
    unsigned short* __restrict__ E,         // [B,S,S] bf16
    float* __restrict__ psum)               // [B*S][32]
{
    __shared__ __attribute__((aligned(16))) unsigned short As[128][64];
    __shared__ __attribute__((aligned(16))) unsigned short Bs[128][64];
    const int S = 2048, D = 512;

    // nwg = 2048; chunked XCD swizzle: tile = (wg%8)*256 + wg/8 (batch-major per XCD)
    int wg = blockIdx.x;
    int tile = (wg & 7) * 256 + (wg >> 3);
    int b = tile >> 8;
    int rem = tile & 255;
    int by = rem >> 4, bx = rem & 15;

    const unsigned short* Ab = Qg + ((long)b * S + by * 128) * D;
    const unsigned short* Bb = Kg + ((long)b * S + bx * 128) * D;
    unsigned short* Eb = E + (long)b * S * S;

    const int tid = threadIdx.x;
    const int lane = tid & 63, w = tid >> 6;
    const int wr = (w >> 1) * 64, wc = (w & 1) * 64;
    const int fr = lane & 15, fq = lane >> 4;

    f32x4 acc[4][4] = {};
    char* Ad = (char*)&As[0][0];
    char* Bd = (char*)&Bs[0][0];

    for (int t = 0; t < 8; ++t) {  // K = 512 = 8 * 64
        const int kk = t * 64;
#pragma unroll
        for (int ti = 0; ti < 4; ++ti) {
            int c = tid + 256 * ti;
            int r = c >> 3, col = (c & 7) << 3;
            int off = (w * 64 + 256 * ti) * 16;
            __builtin_amdgcn_global_load_lds(GLB_AS1(Ab + (long)r * D + kk + col),
                                             LDS_AS3(Ad + off), 16, 0, 0);
            __builtin_amdgcn_global_load_lds(GLB_AS1(Bb + (long)r * D + kk + col),
                                             LDS_AS3(Bd + off), 16, 0, 0);
        }
        __syncthreads();
#pragma unroll
        for (int ks = 0; ks < 2; ++ks) {
            bf16x8 af[4], bv[4];
#pragma unroll
            for (int i = 0; i < 4; ++i)
                af[i] = *(const bf16x8*)&As[wr + i * 16 + fr][ks * 32 + fq * 8];
#pragma unroll
            for (int j = 0; j < 4; ++j)
                bv[j] = *(const bf16x8*)&Bs[wc + j * 16 + fr][ks * 32 + fq * 8];
#pragma unroll
            for (int i = 0; i < 4; ++i)
#pragma unroll
                for (int j = 0; j < 4; ++j)
                    acc[i][j] = __builtin_amdgcn_mfma_f32_16x16x32_bf16(
                        af[i], bv[j], acc[i][j], 0, 0, 0);
        }
        __syncthreads();
    }

    // ---- epilogue: exp2, bf16 store, row partial sums ----
    const float cexp = (float)(1.4426950408889634 / 45.254833995939045);  // log2e/sqrt(2048)
    float ps[4][4];
#pragma unroll
    for (int i = 0; i < 4; ++i)
#pragma unroll
        for (int r = 0; r < 4; ++r) ps[i][r] = 0.f;

#pragma unroll
    for (int i = 0; i < 4; ++i) {
        int row0 = by * 128 + wr + i * 16 + fq * 4;
#pragma unroll
        for (int j = 0; j < 4; ++j) {
            int colc = bx * 128 + wc + j * 16 + fr;
#pragma unroll
            for (int r = 0; r < 4; ++r) {
                float e = exp2f(acc[i][j][r] * cexp);
                unsigned short eb = f2bf(e);
                Eb[(long)(row0 + r) * S + colc] = eb;
                ps[i][r] += bf2f(eb);
            }
        }
    }
#pragma unroll
    for (int i = 0; i < 4; ++i)
#pragma unroll
        for (int r = 0; r < 4; ++r) {
            float v = ps[i][r];
#pragma unroll
            for (int off = 1; off < 16; off <<= 1) v += __shfl_xor(v, off);
            ps[i][r] = v;
        }
    if (fr == 0) {
        int slot = bx * 2 + (w & 1);
#pragma unroll
        for (int i = 0; i < 4; ++i) {
            int row0 = by * 128 + wr + i * 16 + fq * 4;
#pragma unroll
            for (int r = 0; r < 4; ++r)
                psum[((long)b * S + row0 + r) * 32 + slot] = ps[i][r];
        }
    }
}

// ---------------- GEMM2: O = (E VT^T)*inv, fused balanced Pout = E*inv ----------------
// 64x128 tile (M=64), 4 waves (32x64 each), single-buffer LDS 24KB -> grid 1024,
// 4 blocks/CU. Pout: block (by,bx) writes its t-window [8bx,8bx+8) via GLOBAL
// E16 reads (L2-hot) -> no LDS bank conflicts, perfectly balanced.
__global__ __launch_bounds__(256) void gemm_pv_fused(
    const unsigned short* __restrict__ Eg,   // [B,S,S] bf16
    const unsigned short* __restrict__ VTg,  // [B,D,S] bf16
    const float* __restrict__ psum,          // [B*S][32]
    float* __restrict__ Pout,                // [B,S,S] fp32
    float* __restrict__ O)                   // [B,S,D] fp32
{
    __shared__ __attribute__((aligned(16))) unsigned short As[64][64];
    __shared__ __attribute__((aligned(16))) unsigned short Bs[128][64];
    __shared__ float invRow[64];
    const int S = 2048, D = 512;

    // nwg = 1024; chunked XCD swizzle: tile = (wg%8)*128 + wg/8 (batch-major per XCD)
    int wg = blockIdx.x;
    int tile = (wg & 7) * 128 + (wg >> 3);
    int b = tile >> 7;  // 128 tiles (32 by x 4 bx) per batch
    int rem = tile & 127;
    int by = rem >> 2, bx = rem & 3;

    const unsigned short* Ab = Eg + ((long)b * S + by * 64) * S;
    const unsigned short* Bb = VTg + ((long)b * D + bx * 128) * S;
    float* PoutB = Pout + ((long)b * S + by * 64) * S;

    const int tid = threadIdx.x;
    const int lane = tid & 63, w = tid >> 6;
    const int wr = (w >> 1) * 32, wc = (w & 1) * 64;  // wave = 32x64 sub-tile
    const int fr = lane & 15, fq = lane >> 4;

    char* Ad = (char*)&As[0][0];
    char* Bd = (char*)&Bs[0][0];

#define STAGE_PV(k0expr)                                                            \
    {                                                                               \
        const int kk = (k0expr);                                                    \
        _Pragma("unroll") for (int ti = 0; ti < 2; ++ti) {                          \
            int c = tid + 256 * ti;                                                 \
            int r = c >> 3, col = (c & 7) << 3;                                     \
            int off = (w * 64 + 256 * ti) * 16;                                     \
            __builtin_amdgcn_global_load_lds(GLB_AS1(Ab + (long)r * S + kk + col),  \
                                             LDS_AS3(Ad + off), 16, 0, 0);          \
        }                                                                           \
        _Pragma("unroll") for (int ti = 0; ti < 4; ++ti) {                          \
            int c = tid + 256 * ti;                                                 \
            int r = c >> 3, col = (c & 7) << 3;                                     \
            int off = (w * 64 + 256 * ti) * 16;                                     \
            __builtin_amdgcn_global_load_lds(GLB_AS1(Bb + (long)r * S + kk + col),  \
                                             LDS_AS3(Bd + off), 16, 0, 0);          \
        }                                                                           \
    }

    STAGE_PV(0);
    // 1/rowsum for this block's 64 rows (overlaps stage-0 latency)
    if (tid < 64) {
        const float4* p4 = (const float4*)(psum + ((long)b * S + by * 64 + tid) * 32);
        float s = 0.f;
#pragma unroll
        for (int i = 0; i < 8; ++i) {
            float4 v = p4[i];
            s += v.x + v.y + v.z + v.w;
        }
        invRow[tid] = 1.0f / s;
    }
    f32x4 acc[2][4] = {};
    __syncthreads();

    // Pout-writer mapping: thread -> (row = tid>>2, 16-col chunk = tid&3)
    const int prRow = tid >> 2, prC0 = (tid & 3) * 16;
    const float ivP = invRow[prRow];

    for (int t = 0; t < 32; ++t) {  // K = 2048 = 32 * 64
#pragma unroll
        for (int ks = 0; ks < 2; ++ks) {
            bf16x8 af[2], bv[4];
#pragma unroll
            for (int i = 0; i < 2; ++i)
                af[i] = *(const bf16x8*)&As[wr + i * 16 + fr][ks * 32 + fq * 8];
#pragma unroll
            for (int j = 0; j < 4; ++j)
                bv[j] = *(const bf16x8*)&Bs[wc + j * 16 + fr][ks * 32 + fq * 8];
#pragma unroll
            for (int i = 0; i < 2; ++i)
#pragma unroll
                for (int j = 0; j < 4; ++j)
                    acc[i][j] = __builtin_amdgcn_mfma_f32_16x16x32_bf16(
                        af[i], bv[j], acc[i][j], 0, 0, 0);
        }
        // fused Pout for our t-window: global E16 read (L2-hot), fp32 write
        if ((t >> 3) == bx) {
            const unsigned short* esrc = Ab + (long)prRow * S + t * 64 + prC0;
            float* pdst = PoutB + (long)prRow * S + t * 64 + prC0;
            u16x8 e0 = *(const u16x8*)esrc;
            u16x8 e1 = *(const u16x8*)(esrc + 8);
            float4 o0 = {bf2f(e0[0]) * ivP, bf2f(e0[1]) * ivP, bf2f(e0[2]) * ivP, bf2f(e0[3]) * ivP};
            float4 o1 = {bf2f(e0[4]) * ivP, bf2f(e0[5]) * ivP, bf2f(e0[6]) * ivP, bf2f(e0[7]) * ivP};
            float4 o2 = {bf2f(e1[0]) * ivP, bf2f(e1[1]) * ivP, bf2f(e1[2]) * ivP, bf2f(e1[3]) * ivP};
            float4 o3 = {bf2f(e1[4]) * ivP, bf2f(e1[5]) * ivP, bf2f(e1[6]) * ivP, bf2f(e1[7]) * ivP};
            *(float4*)(pdst) = o0;
            *(float4*)(pdst + 4) = o1;
            *(float4*)(pdst + 8) = o2;
            *(float4*)(pdst + 12) = o3;
        }
        __syncthreads();  // LDS consumption of tile t done
        if (t < 31) {
            STAGE_PV((t + 1) * 64);
            __syncthreads();  // tile t+1 staged (implicit vmcnt drain)
        }
    }
#undef STAGE_PV

    // ---- epilogue: O = acc * inv[row] ----
#pragma unroll
    for (int i = 0; i < 2; ++i) {
        int lr0 = wr + i * 16 + fq * 4;
        float iv[4];
#pragma unroll
        for (int r = 0; r < 4; ++r) iv[r] = invRow[lr0 + r];
        int row0 = by * 64 + lr0;
#pragma unroll
        for (int j = 0; j < 4; ++j) {
            int colc = bx * 128 + wc + j * 16 + fr;
#pragma unroll
            for (int r = 0; r < 4; ++r)
                O[((long)b * S + row0 + r) * D + colc] = acc[i][j][r] * iv[r];
        }
    }
}

extern "C" void kernel_launch(void* const* d_in, const int* in_sizes, int n_in,
                              void* d_out, int out_size, void* d_ws, size_t ws_size,
                              hipStream_t stream) {
    const int B = 8, S = 2048, D = 512;
    const float* q = (const float*)d_in[0];
    const float* k = (const float*)d_in[1];
    const float* v = (const float*)d_in[2];

    float* Oout = (float*)d_out;             // [B,S,D]
    float* Pout = Oout + (size_t)B * S * D;  // [B,S,S]

    unsigned short* Q16 = (unsigned short*)d_ws;      // B*S*D bf16
    unsigned short* K16 = Q16 + (size_t)B * S * D;    // B*S*D bf16
    unsigned short* VT16 = K16 + (size_t)B * S * D;   // B*D*S bf16
    unsigned short* E16 = VT16 + (size_t)B * S * D;   // B*S*S bf16
    float* psum = (float*)(E16 + (size_t)B * S * S);  // B*S*32 fp32

    int n4 = B * S * D / 4;
    conv_qk<<<dim3(n4 / 256, 2), 256, 0, stream>>>((const float4*)q, (const float4*)k,
                                                   (ushort4*)Q16, (ushort4*)K16, n4);
    transpose_conv<<<dim3(D / 32, S / 32, B), dim3(32, 8), 0, stream>>>(v, VT16, S, D);

    gemm_qk_exp<<<2048, 256, 0, stream>>>(Q16, K16, E16, psum);

    gemm_pv_fused<<<1024, 256, 0, stream>>>(E16, VT16, psum, Pout, Oout);
}

// Round 6
// 359.565 us; speedup vs baseline: 1.1923x; 1.0502x over previous
//
#include <hip/hip_runtime.h>
#include <hip/hip_bf16.h>

typedef __attribute__((ext_vector_type(8))) short bf16x8;
typedef __attribute__((ext_vector_type(4))) float f32x4;
typedef __attribute__((ext_vector_type(8))) unsigned short u16x8;

#define LDS_AS3(p) ((__attribute__((address_space(3))) void*)(p))
#define GLB_AS1(p) ((const __attribute__((address_space(1))) void*)(p))

__device__ inline unsigned short f2bf(float f) {
    unsigned int x = __float_as_uint(f);
    unsigned int r = (x + 0x7fffu + ((x >> 16) & 1u)) >> 16;  // RNE, no NaN in data
    return (unsigned short)r;
}
__device__ inline float bf2f(unsigned short b) {
    return __uint_as_float(((unsigned int)b) << 16);
}

// ---------------- fp32 -> bf16 for Q and K (grid.y selects input) ----------------
__global__ __launch_bounds__(256) void conv_qk(const float4* __restrict__ q,
                                               const float4* __restrict__ k,
                                               ushort4* __restrict__ Q16,
                                               ushort4* __restrict__ K16, int n4) {
    const float4* in = blockIdx.y ? k : q;
    ushort4* out = blockIdx.y ? K16 : Q16;
    int i = blockIdx.x * 256 + threadIdx.x;
    if (i < n4) {
        float4 f = in[i];
        ushort4 o;
        o.x = f2bf(f.x); o.y = f2bf(f.y); o.z = f2bf(f.z); o.w = f2bf(f.w);
        out[i] = o;
    }
}

// ---------------- V [S,D] fp32 -> VT [D,S] bf16 (per batch) ----------------
__global__ __launch_bounds__(256) void transpose_conv(const float* __restrict__ V,
                                                      unsigned short* __restrict__ VT,
                                                      int rows, int cols) {
    __shared__ unsigned short tile[32][33];
    long b = blockIdx.z;
    V  += b * (long)rows * cols;
    VT += b * (long)rows * cols;
    int n0 = blockIdx.x * 32, k0 = blockIdx.y * 32;
    int tx = threadIdx.x, ty = threadIdx.y;
#pragma unroll
    for (int j = 0; j < 4; ++j)
        tile[ty + j * 8][tx] = f2bf(V[(long)(k0 + ty + j * 8) * cols + n0 + tx]);
    __syncthreads();
#pragma unroll
    for (int j = 0; j < 4; ++j)
        VT[(long)(n0 + ty + j * 8) * rows + k0 + tx] = tile[tx][ty + j * 8];
}

// ---------------- GEMM1: E = exp2(c * Q K^T) bf16 + row-sum partials ----------------
// 128x128 tile, 4 waves, BK=32, DOUBLE-buffered LDS (32KB total -> 5 blocks/CU),
// T3-minimum 2-phase: STAGE(t+1) issued BEFORE compute(t), ONE barrier per K-step
// (its vmcnt(0) drain lands after compute -> load latency hidden under MFMA).
__global__ __launch_bounds__(256) void gemm_qk_exp(
    const unsigned short* __restrict__ Qg,  // [B,S,D] bf16
    const unsigned short* __restrict__ Kg,  // [B,S,D] bf16
    unsigned short* __restrict__ E,         // [B,S,S] bf16
    float* __restrict__ psum)               // [B*S][32]
{
    __shared__ __attribute__((aligned(16))) unsigned short As[2][128][32];
    __shared__ __attribute__((aligned(16))) unsigned short Bs[2][128][32];
    const int S = 2048, D = 512;

    // nwg = 2048; chunked XCD swizzle (batch-major: XCD i owns batch i)
    int wg = blockIdx.x;
    int tile = (wg & 7) * 256 + (wg >> 3);
    int b = tile >> 8;
    int rem = tile & 255;
    int by = rem >> 4, bx = rem & 15;

    const unsigned short* Ab = Qg + ((long)b * S + by * 128) * D;
    const unsigned short* Bb = Kg + ((long)b * S + bx * 128) * D;
    unsigned short* Eb = E + (long)b * S * S;

    const int tid = threadIdx.x;
    const int lane = tid & 63, w = tid >> 6;
    const int wr = (w >> 1) * 64, wc = (w & 1) * 64;
    const int fr = lane & 15, fq = lane >> 4;

    f32x4 acc[4][4] = {};

    // 128x32 bf16 tile = 8KB = 512 x 16B chunks; c = tid + 256*ti; 4 chunks/row
#define STAGE1(buf, k0expr)                                                        \
    {                                                                              \
        const int kk = (k0expr);                                                   \
        char* Ad = (char*)&As[buf][0][0];                                          \
        char* Bd = (char*)&Bs[buf][0][0];                                          \
        _Pragma("unroll") for (int ti = 0; ti < 2; ++ti) {                         \
            int c = tid + 256 * ti;                                                \
            int r = c >> 2, col = (c & 3) << 3;                                    \
            int off = (w * 64 + 256 * ti) * 16;                                    \
            __builtin_amdgcn_global_load_lds(GLB_AS1(Ab + (long)r * D + kk + col), \
                                             LDS_AS3(Ad + off), 16, 0, 0);         \
            __builtin_amdgcn_global_load_lds(GLB_AS1(Bb + (long)r * D + kk + col), \
                                             LDS_AS3(Bd + off), 16, 0, 0);         \
        }                                                                          \
    }

    STAGE1(0, 0);
    __syncthreads();

    for (int t = 0; t < 16; ++t) {  // K = 512 = 16 * 32
        int cur = t & 1;
        if (t < 15) STAGE1(cur ^ 1, (t + 1) * 32);  // issue loads FIRST
        bf16x8 af[4], bv[4];
#pragma unroll
        for (int i = 0; i < 4; ++i)
            af[i] = *(const bf16x8*)&As[cur][wr + i * 16 + fr][fq * 8];
#pragma unroll
        for (int j = 0; j < 4; ++j)
            bv[j] = *(const bf16x8*)&Bs[cur][wc + j * 16 + fr][fq * 8];
#pragma unroll
        for (int i = 0; i < 4; ++i)
#pragma unroll
            for (int j = 0; j < 4; ++j)
                acc[i][j] = __builtin_amdgcn_mfma_f32_16x16x32_bf16(
                    af[i], bv[j], acc[i][j], 0, 0, 0);
        __syncthreads();  // single barrier: drains loads (buf^1 ready), guards buf reuse
    }
#undef STAGE1

    // ---- epilogue: exp2, bf16 store, row partial sums ----
    const float cexp = (float)(1.4426950408889634 / 45.254833995939045);  // log2e/sqrt(2048)
    float ps[4][4];
#pragma unroll
    for (int i = 0; i < 4; ++i)
#pragma unroll
        for (int r = 0; r < 4; ++r) ps[i][r] = 0.f;

#pragma unroll
    for (int i = 0; i < 4; ++i) {
        int row0 = by * 128 + wr + i * 16 + fq * 4;
#pragma unroll
        for (int j = 0; j < 4; ++j) {
            int colc = bx * 128 + wc + j * 16 + fr;
#pragma unroll
            for (int r = 0; r < 4; ++r) {
                float e = exp2f(acc[i][j][r] * cexp);
                unsigned short eb = f2bf(e);
                Eb[(long)(row0 + r) * S + colc] = eb;
                ps[i][r] += bf2f(eb);
            }
        }
    }
#pragma unroll
    for (int i = 0; i < 4; ++i)
#pragma unroll
        for (int r = 0; r < 4; ++r) {
            float v = ps[i][r];
#pragma unroll
            for (int off = 1; off < 16; off <<= 1) v += __shfl_xor(v, off);
            ps[i][r] = v;
        }
    if (fr == 0) {
        int slot = bx * 2 + (w & 1);
#pragma unroll
        for (int i = 0; i < 4; ++i) {
            int row0 = by * 128 + wr + i * 16 + fq * 4;
#pragma unroll
            for (int r = 0; r < 4; ++r)
                psum[((long)b * S + row0 + r) * 32 + slot] = ps[i][r];
        }
    }
}

// ---------------- GEMM2: O = (E VT^T)*inv, fused balanced Pout = E*inv ----------------
// 64x128 tile, 4 waves (32x64), BK=32, dbuf LDS 24KB, grid 1024 (4 blocks/CU exact),
// same single-barrier 2-phase. Pout: block (by,bx) writes t-window [16bx,16bx+16)
// from GLOBAL E16 (L2-hot), balanced across all blocks.
__global__ __launch_bounds__(256) void gemm_pv_fused(
    const unsigned short* __restrict__ Eg,   // [B,S,S] bf16
    const unsigned short* __restrict__ VTg,  // [B,D,S] bf16
    const float* __restrict__ psum,          // [B*S][32]
    float* __restrict__ Pout,                // [B,S,S] fp32
    float* __restrict__ O)                   // [B,S,D] fp32
{
    __shared__ __attribute__((aligned(16))) unsigned short As[2][64][32];
    __shared__ __attribute__((aligned(16))) unsigned short Bs[2][128][32];
    __shared__ float invRow[64];
    const int S = 2048, D = 512;

    // nwg = 1024; chunked XCD swizzle (batch-major per XCD)
    int wg = blockIdx.x;
    int tile = (wg & 7) * 128 + (wg >> 3);
    int b = tile >> 7;
    int rem = tile & 127;
    int by = rem >> 2, bx = rem & 3;

    const unsigned short* Ab = Eg + ((long)b * S + by * 64) * S;
    const unsigned short* Bb = VTg + ((long)b * D + bx * 128) * S;
    float* PoutB = Pout + ((long)b * S + by * 64) * S;

    const int tid = threadIdx.x;
    const int lane = tid & 63, w = tid >> 6;
    const int wr = (w >> 1) * 32, wc = (w & 1) * 64;
    const int fr = lane & 15, fq = lane >> 4;

#define STAGE_PV(buf, k0expr)                                                       \
    {                                                                               \
        const int kk = (k0expr);                                                    \
        char* Ad = (char*)&As[buf][0][0];                                           \
        char* Bd = (char*)&Bs[buf][0][0];                                           \
        {                                                                           \
            int c = tid;                                                            \
            int r = c >> 2, col = (c & 3) << 3;                                     \
            int off = (w * 64) * 16;                                                \
            __builtin_amdgcn_global_load_lds(GLB_AS1(Ab + (long)r * S + kk + col),  \
                                             LDS_AS3(Ad + off), 16, 0, 0);          \
        }                                                                           \
        _Pragma("unroll") for (int ti = 0; ti < 2; ++ti) {                          \
            int c = tid + 256 * ti;                                                 \
            int r = c >> 2, col = (c & 3) << 3;                                     \
            int off = (w * 64 + 256 * ti) * 16;                                     \
            __builtin_amdgcn_global_load_lds(GLB_AS1(Bb + (long)r * S + kk + col),  \
                                             LDS_AS3(Bd + off), 16, 0, 0);          \
        }                                                                           \
    }

    STAGE_PV(0, 0);
    // 1/rowsum for this block's 64 rows (overlaps stage-0 latency)
    if (tid < 64) {
        const float4* p4 = (const float4*)(psum + ((long)b * S + by * 64 + tid) * 32);
        float s = 0.f;
#pragma unroll
        for (int i = 0; i < 8; ++i) {
            float4 v = p4[i];
            s += v.x + v.y + v.z + v.w;
        }
        invRow[tid] = 1.0f / s;
    }
    f32x4 acc[2][4] = {};
    __syncthreads();

    // Pout-writer mapping: row = tid>>2 (0..63), 8-col chunk = tid&3
    const int prRow = tid >> 2, prC0 = (tid & 3) * 8;
    const float ivP = invRow[prRow];

    for (int t = 0; t < 64; ++t) {  // K = 2048 = 64 * 32
        int cur = t & 1;
        if (t < 63) STAGE_PV(cur ^ 1, (t + 1) * 32);  // issue loads FIRST
        bf16x8 af[2], bv[4];
#pragma unroll
        for (int i = 0; i < 2; ++i)
            af[i] = *(const bf16x8*)&As[cur][wr + i * 16 + fr][fq * 8];
#pragma unroll
        for (int j = 0; j < 4; ++j)
            bv[j] = *(const bf16x8*)&Bs[cur][wc + j * 16 + fr][fq * 8];
#pragma unroll
        for (int i = 0; i < 2; ++i)
#pragma unroll
            for (int j = 0; j < 4; ++j)
                acc[i][j] = __builtin_amdgcn_mfma_f32_16x16x32_bf16(
                    af[i], bv[j], acc[i][j], 0, 0, 0);
        // fused Pout for our t-window: global E16 read (L2-hot), fp32 write
        if ((t >> 4) == bx) {
            const unsigned short* esrc = Ab + (long)prRow * S + t * 32 + prC0;
            float* pdst = PoutB + (long)prRow * S + t * 32 + prC0;
            u16x8 e0 = *(const u16x8*)esrc;
            float4 o0 = {bf2f(e0[0]) * ivP, bf2f(e0[1]) * ivP, bf2f(e0[2]) * ivP, bf2f(e0[3]) * ivP};
            float4 o1 = {bf2f(e0[4]) * ivP, bf2f(e0[5]) * ivP, bf2f(e0[6]) * ivP, bf2f(e0[7]) * ivP};
            *(float4*)(pdst) = o0;
            *(float4*)(pdst + 4) = o1;
        }
        __syncthreads();  // single barrier per K-step
    }
#undef STAGE_PV

    // ---- epilogue: O = acc * inv[row] ----
#pragma unroll
    for (int i = 0; i < 2; ++i) {
        int lr0 = wr + i * 16 + fq * 4;
        float iv[4];
#pragma unroll
        for (int r = 0; r < 4; ++r) iv[r] = invRow[lr0 + r];
        int row0 = by * 64 + lr0;
#pragma unroll
        for (int j = 0; j < 4; ++j) {
            int colc = bx * 128 + wc + j * 16 + fr;
#pragma unroll
            for (int r = 0; r < 4; ++r)
                O[((long)b * S + row0 + r) * D + colc] = acc[i][j][r] * iv[r];
        }
    }
}

extern "C" void kernel_launch(void* const* d_in, const int* in_sizes, int n_in,
                              void* d_out, int out_size, void* d_ws, size_t ws_size,
                              hipStream_t stream) {
    const int B = 8, S = 2048, D = 512;
    const float* q = (const float*)d_in[0];
    const float* k = (const float*)d_in[1];
    const float* v = (const float*)d_in[2];

    float* Oout = (float*)d_out;             // [B,S,D]
    float* Pout = Oout + (size_t)B * S * D;  // [B,S,S]

    unsigned short* Q16 = (unsigned short*)d_ws;      // B*S*D bf16
    unsigned short* K16 = Q16 + (size_t)B * S * D;    // B*S*D bf16
    unsigned short* VT16 = K16 + (size_t)B * S * D;   // B*D*S bf16
    unsigned short* E16 = VT16 + (size_t)B * S * D;   // B*S*S bf16
    float* psum = (float*)(E16 + (size_t)B * S * S);  // B*S*32 fp32

    int n4 = B * S * D / 4;
    conv_qk<<<dim3(n4 / 256, 2), 256, 0, stream>>>((const float4*)q, (const float4*)k,
                                                   (ushort4*)Q16, (ushort4*)K16, n4);
    transpose_conv<<<dim3(D / 32, S / 32, B), dim3(32, 8), 0, stream>>>(v, VT16, S, D);

    gemm_qk_exp<<<2048, 256, 0, stream>>>(Q16, K16, E16, psum);

    gemm_pv_fused<<<1024, 256, 0, stream>>>(E16, VT16, psum, Pout, Oout);
}